// Round 4
// baseline (995.945 us; speedup 1.0000x reference)
//
#include <hip/hip_runtime.h>
#include <hip/hip_bf16.h>
#include <float.h>

#define N_CAT   100000
#define N_USERS 50000
#define N_REL   32
#define D       64
#define NEDGE   1600000
#define NNZ     1000000
#define NBINS   (N_CAT + N_USERS)          // 150000 fine bins
#define SCAN_B  ((NBINS + 255) / 256)      // 586 scan blocks
#define NBK_E   ((N_CAT + 63) / 64)        // 1563 coarse edge buckets (head>>6)
#define NBK_U   ((N_USERS + 63) / 64)      // 782 coarse user buckets (row>>6)
#define NBK     (NBK_E + NBK_U)

// ---------------------------------------------------------------------------
// ws layout:
//   norm2     : N_CAT*N_REL floats (12.8 MB)
//   cnt/offs/fcur : NBINS ints each (1.8 MB)
//   bsum      : SCAN_B ints
//   ccur      : NBK ints (coarse cursors)
//   sorted_ta : NEDGE int  (6.4 MB)  packed edge recs, coarse- then fine-sorted
//   sorted_cv : NNZ  int2  (8.0 MB)  {col|row_lo, val}, coarse- then fine-sorted
// total ~29 MB
// ---------------------------------------------------------------------------

__global__ void norm2_kernel(const float* __restrict__ cat,
                             const float* __restrict__ W,
                             float* __restrict__ norm2) {
    int gid = blockIdx.x * blockDim.x + threadIdx.x;
    if (gid >= N_CAT * N_REL) return;
    int node = gid >> 5;
    int rel  = gid & 31;
    const float4* c = (const float4*)(cat + (size_t)node * D);
    const float4* w = (const float4*)(W + (size_t)rel * D);
    float s = 0.f;
#pragma unroll
    for (int i = 0; i < 16; ++i) {
        float4 a = c[i], b = w[i];
        float p0 = a.x * b.x, p1 = a.y * b.y, p2 = a.z * b.z, p3 = a.w * b.w;
        s += p0 * p0 + p1 * p1 + p2 * p2 + p3 * p3;
    }
    norm2[gid] = s;
}

__global__ void hist_kernel(const int* __restrict__ head,
                            const int* __restrict__ imr,
                            int* __restrict__ cnt) {
    int gid = blockIdx.x * blockDim.x + threadIdx.x;
    if (gid < NEDGE) {
        atomicAdd(&cnt[head[gid]], 1);
    } else if (gid < NEDGE + NNZ) {
        atomicAdd(&cnt[N_CAT + imr[gid - NEDGE]], 1);
    }
}

__global__ void scan1_kernel(const int* __restrict__ cnt,
                             int* __restrict__ offs,
                             int* __restrict__ bsum) {
    __shared__ int s[256];
    int t = threadIdx.x;
    int i = blockIdx.x * 256 + t;
    int v = (i < NBINS) ? cnt[i] : 0;
    s[t] = v;
    __syncthreads();
#pragma unroll
    for (int off = 1; off < 256; off <<= 1) {
        int x = (t >= off) ? s[t - off] : 0;
        __syncthreads();
        s[t] += x;
        __syncthreads();
    }
    if (i < NBINS) offs[i] = s[t] - v;
    if (t == 255) bsum[blockIdx.x] = s[t];
}

__global__ void scan2_kernel(int* __restrict__ bsum) {
    __shared__ int s[1024];
    int t = threadIdx.x;
    int v = (t < SCAN_B) ? bsum[t] : 0;
    s[t] = v;
    __syncthreads();
#pragma unroll
    for (int off = 1; off < 1024; off <<= 1) {
        int x = (t >= off) ? s[t - off] : 0;
        __syncthreads();
        s[t] += x;
        __syncthreads();
    }
    if (t < SCAN_B) bsum[t] = s[t] - v;
}

__global__ void scan3_kernel(int* __restrict__ offs,
                             const int* __restrict__ bsum,
                             int* __restrict__ fcur) {
    int i = blockIdx.x * 256 + threadIdx.x;
    if (i >= NBINS) return;
    int o = offs[i] + bsum[i >> 8];
    offs[i] = o;
    fcur[i] = o;
}

__global__ void init_ccur_kernel(const int* __restrict__ offs,
                                 int* __restrict__ ccur) {
    int k = blockIdx.x * 256 + threadIdx.x;
    if (k < NBK_E)      ccur[k] = offs[k << 6];
    else if (k < NBK)   ccur[k] = offs[N_CAT + ((k - NBK_E) << 6)];
}

// coarse pass: sequential-append into ~2.3K buckets (open-line set ~150 KB, L2-hot)
__global__ void bucket_scatter_kernel(const int* __restrict__ head,
                                      const int* __restrict__ tail,
                                      const int* __restrict__ etype,
                                      const int* __restrict__ imr,
                                      const int* __restrict__ imc,
                                      const float* __restrict__ imv,
                                      int* __restrict__ ccur,
                                      int* __restrict__ sorted_ta,
                                      int2* __restrict__ sorted_cv) {
    int gid = blockIdx.x * blockDim.x + threadIdx.x;
    if (gid < NEDGE) {
        int h = head[gid], t = tail[gid], r = etype[gid] - 1;
        int pos = atomicAdd(&ccur[h >> 6], 1);
        sorted_ta[pos] = ((h & 63) << 22) | (t << 5) | r;   // 6+17+5 = 28 bits
    } else if (gid < NEDGE + NNZ) {
        int n = gid - NEDGE;
        int rr = imr[n];
        int pos = atomicAdd(&ccur[NBK_E + (rr >> 6)], 1) - NEDGE;
        sorted_cv[pos] = make_int2(((rr & 63) << 17) | imc[n], __float_as_int(imv[n]));
    }
}

// fine pass: one workgroup per bucket; stage bucket to LDS, scatter in place
// (all final positions lie inside this bucket's own region)
__global__ void bucket_sort_kernel(const int* __restrict__ offs,
                                   int* __restrict__ fcur,
                                   int* __restrict__ sorted_ta,
                                   int2* __restrict__ sorted_cv) {
    __shared__ int lds[8192];                 // 32 KB
    int b = blockIdx.x, tid = threadIdx.x;
    if (b < NBK_E) {
        int h0 = b << 6;
        int s = offs[h0];
        int hend = min(h0 + 64, N_CAT);
        int e = (hend == N_CAT) ? NEDGE : offs[hend];
        int n = min(e - s, 8192);
        for (int i = tid; i < n; i += 256) lds[i] = sorted_ta[s + i];
        __syncthreads();
        for (int i = tid; i < n; i += 256) {
            int rec  = lds[i];
            int h    = h0 | (rec >> 22);
            int pos  = atomicAdd(&fcur[h], 1);
            sorted_ta[pos] = rec & 0x3FFFFF;  // (tail<<5)|rel
        }
    } else {
        int k = b - NBK_E;
        int u0 = k << 6;
        int s = offs[N_CAT + u0] - NEDGE;
        int uend = min(u0 + 64, N_USERS);
        int e = ((uend == N_USERS) ? (NEDGE + NNZ) : offs[N_CAT + uend]) - NEDGE;
        int2* lds2 = (int2*)lds;              // 4096 recs
        int n = min(e - s, 4096);
        for (int i = tid; i < n; i += 256) lds2[i] = sorted_cv[s + i];
        __syncthreads();
        for (int i = tid; i < n; i += 256) {
            int2 rec = lds2[i];
            int row  = u0 | (rec.x >> 17);
            int pos  = atomicAdd(&fcur[N_CAT + row], 1) - NEDGE;
            sorted_cv[pos] = make_int2(rec.x & 0x1FFFF, rec.y);
        }
    }
}

// one wave per head; fast path deg<=64: single record read, softmax in registers
__global__ void cat_agg_sorted_kernel(const int* __restrict__ offs,
                                      const int* __restrict__ sorted_ta,
                                      const float* __restrict__ norm2,
                                      const float* __restrict__ cat,
                                      const float* __restrict__ W,
                                      float* __restrict__ cat_agg) {
    int wv   = threadIdx.x >> 6;
    int lane = threadIdx.x & 63;
    int h = blockIdx.x * 4 + wv;
    int start = offs[h];
    int end   = offs[h + 1];                  // offs[N_CAT] == NEDGE
    int deg   = end - start;

    float a0 = 0.f, a1 = 0.f, a2 = 0.f, a3 = 0.f;

    if (deg <= 64) {
        int   rec = 0;
        float att = -FLT_MAX;
        if (lane < deg) {
            rec = sorted_ta[start + lane];
            int t = rec >> 5, r = rec & 31;
            att = norm2[h * N_REL + r] * norm2[(size_t)t * N_REL + r];
        }
        float m = att;
#pragma unroll
        for (int off = 32; off > 0; off >>= 1) m = fmaxf(m, __shfl_xor(m, off));
        float ex = (lane < deg) ? __expf(att - m) : 0.f;
        float ssum = ex;
#pragma unroll
        for (int off = 32; off > 0; off >>= 1) ssum += __shfl_xor(ssum, off);
        float w = (deg > 0) ? ex / ssum : 0.f;

        int j = 0;
        for (; j + 4 <= deg; j += 4) {
            int   tr0 = __shfl(rec, j + 0), tr1 = __shfl(rec, j + 1);
            int   tr2 = __shfl(rec, j + 2), tr3 = __shfl(rec, j + 3);
            float w0  = __shfl(w,   j + 0), w1  = __shfl(w,   j + 1);
            float w2  = __shfl(w,   j + 2), w3  = __shfl(w,   j + 3);
            a0 += w0 * cat[(size_t)(tr0 >> 5) * D + lane] * W[(tr0 & 31) * D + lane];
            a1 += w1 * cat[(size_t)(tr1 >> 5) * D + lane] * W[(tr1 & 31) * D + lane];
            a2 += w2 * cat[(size_t)(tr2 >> 5) * D + lane] * W[(tr2 & 31) * D + lane];
            a3 += w3 * cat[(size_t)(tr3 >> 5) * D + lane] * W[(tr3 & 31) * D + lane];
        }
        for (; j < deg; ++j) {
            int   tr = __shfl(rec, j);
            float ww = __shfl(w,   j);
            a0 += ww * cat[(size_t)(tr >> 5) * D + lane] * W[(tr & 31) * D + lane];
        }
    } else {
        // generic path (statistically never taken at avg degree 16)
        float m = -FLT_MAX;
        for (int j = lane; j < deg; j += 64) {
            int rec = sorted_ta[start + j];
            int t = rec >> 5, r = rec & 31;
            m = fmaxf(m, norm2[h * N_REL + r] * norm2[(size_t)t * N_REL + r]);
        }
#pragma unroll
        for (int off = 32; off > 0; off >>= 1) m = fmaxf(m, __shfl_xor(m, off));
        float ssum = 0.f;
        for (int j = lane; j < deg; j += 64) {
            int rec = sorted_ta[start + j];
            int t = rec >> 5, r = rec & 31;
            ssum += __expf(norm2[h * N_REL + r] * norm2[(size_t)t * N_REL + r] - m);
        }
#pragma unroll
        for (int off = 32; off > 0; off >>= 1) ssum += __shfl_xor(ssum, off);
        float inv = 1.f / ssum;
        for (int j0 = 0; j0 < deg; j0 += 64) {
            int n = min(64, deg - j0);
            int   rec = 0;
            float w   = 0.f;
            if (lane < n) {
                rec = sorted_ta[start + j0 + lane];
                int t = rec >> 5, r = rec & 31;
                w = __expf(norm2[h * N_REL + r] * norm2[(size_t)t * N_REL + r] - m) * inv;
            }
            for (int j = 0; j < n; ++j) {
                int   tr = __shfl(rec, j);
                float ww = __shfl(w,   j);
                a0 += ww * cat[(size_t)(tr >> 5) * D + lane] * W[(tr & 31) * D + lane];
            }
        }
    }
    cat_agg[(size_t)h * D + lane] = (a0 + a1) + (a2 + a3);
}

__global__ void spmm_user_kernel(const int* __restrict__ offs,
                                 const int2* __restrict__ sorted_cv,
                                 const float* __restrict__ cat,
                                 const float* __restrict__ uemb,
                                 const float* __restrict__ W,
                                 float* __restrict__ uagg) {
    __shared__ float s_user[4][D];
    __shared__ float s_score[4][N_REL];
    int wv   = threadIdx.x >> 6;
    int lane = threadIdx.x & 63;
    int u = blockIdx.x * 4 + wv;
    int start = offs[N_CAT + u] - NEDGE;
    int end   = (u == N_USERS - 1) ? NNZ : offs[N_CAT + u + 1] - NEDGE;
    int deg   = end - start;

    float a0 = 0.f, a1 = 0.f, a2 = 0.f, a3 = 0.f;
    for (int j0 = 0; j0 < deg; j0 += 64) {
        int n = min(64, deg - j0);
        int   my_c = 0;
        float my_v = 0.f;
        if (lane < n) {
            int2 cv = sorted_cv[start + j0 + lane];
            my_c = cv.x;
            my_v = __int_as_float(cv.y);
        }
        int j = 0;
        for (; j + 4 <= n; j += 4) {
            int   c0 = __shfl(my_c, j + 0), c1 = __shfl(my_c, j + 1);
            int   c2 = __shfl(my_c, j + 2), c3 = __shfl(my_c, j + 3);
            float v0 = __shfl(my_v, j + 0), v1 = __shfl(my_v, j + 1);
            float v2 = __shfl(my_v, j + 2), v3 = __shfl(my_v, j + 3);
            a0 += v0 * cat[(size_t)c0 * D + lane];
            a1 += v1 * cat[(size_t)c1 * D + lane];
            a2 += v2 * cat[(size_t)c2 * D + lane];
            a3 += v3 * cat[(size_t)c3 * D + lane];
        }
        for (; j < n; ++j) {
            int   c = __shfl(my_c, j);
            float v = __shfl(my_v, j);
            a0 += v * cat[(size_t)c * D + lane];
        }
    }
    float acc = (a0 + a1) + (a2 + a3);

    s_user[wv][lane] = uemb[(size_t)u * D + lane];
    __syncthreads();

    if (lane < N_REL) {
        float dot = 0.f;
#pragma unroll
        for (int d = 0; d < D; ++d) dot += s_user[wv][d] * W[lane * D + d];
        float mm = dot;
#pragma unroll
        for (int off = 16; off > 0; off >>= 1) mm = fmaxf(mm, __shfl_xor(mm, off));
        float ex = __expf(dot - mm);
        float sm = ex;
#pragma unroll
        for (int off = 16; off > 0; off >>= 1) sm += __shfl_xor(sm, off);
        s_score[wv][lane] = ex / sm;
    }
    __syncthreads();

    float proj = 0.f;
#pragma unroll
    for (int r = 0; r < N_REL; ++r) proj += s_score[wv][r] * W[r * D + lane];

    uagg[(size_t)u * D + lane] = acc * (1.f + proj);
}

extern "C" void kernel_launch(void* const* d_in, const int* in_sizes, int n_in,
                              void* d_out, int out_size, void* d_ws, size_t ws_size,
                              hipStream_t stream) {
    const float* cat   = (const float*)d_in[0];
    const float* uemb  = (const float*)d_in[1];
    const int*   eidx  = (const int*)d_in[2];
    const int*   etype = (const int*)d_in[3];
    const int*   imr   = (const int*)d_in[4];
    const int*   imc   = (const int*)d_in[5];
    const float* imv   = (const float*)d_in[6];
    const float* W     = (const float*)d_in[7];
    const int* head = eidx;
    const int* tail = eidx + NEDGE;

    float* out     = (float*)d_out;
    float* cat_agg = out;                         // [N_CAT, D]
    float* uagg    = out + (size_t)N_CAT * D;     // [N_USERS, D]

    float* norm2   = (float*)d_ws;
    int*   cnt     = (int*)(norm2 + (size_t)N_CAT * N_REL);
    int*   offs    = cnt + NBINS;
    int*   fcur    = offs + NBINS;
    int*   bsum    = fcur + NBINS;
    int*   ccur    = bsum + SCAN_B;
    int*   sorted_ta = ccur + ((NBK + 1) & ~1);
    int2*  sorted_cv = (int2*)(sorted_ta + ((NEDGE + 1) & ~1));

    hipMemsetAsync(cnt, 0, (size_t)NBINS * sizeof(int), stream);

    hist_kernel<<<(NEDGE + NNZ + 255) / 256, 256, 0, stream>>>(head, imr, cnt);
    scan1_kernel<<<SCAN_B, 256, 0, stream>>>(cnt, offs, bsum);
    scan2_kernel<<<1, 1024, 0, stream>>>(bsum);
    scan3_kernel<<<SCAN_B, 256, 0, stream>>>(offs, bsum, fcur);
    init_ccur_kernel<<<(NBK + 255) / 256, 256, 0, stream>>>(offs, ccur);
    bucket_scatter_kernel<<<(NEDGE + NNZ + 255) / 256, 256, 0, stream>>>(
        head, tail, etype, imr, imc, imv, ccur, sorted_ta, sorted_cv);
    bucket_sort_kernel<<<NBK, 256, 0, stream>>>(offs, fcur, sorted_ta, sorted_cv);
    norm2_kernel<<<(N_CAT * N_REL + 255) / 256, 256, 0, stream>>>(cat, W, norm2);
    cat_agg_sorted_kernel<<<N_CAT / 4, 256, 0, stream>>>(offs, sorted_ta, norm2, cat, W, cat_agg);
    spmm_user_kernel<<<N_USERS / 4, 256, 0, stream>>>(offs, sorted_cv, cat, uemb, W, uagg);
}

// Round 5
// 462.440 us; speedup vs baseline: 2.1537x; 2.1537x over previous
//
#include <hip/hip_runtime.h>
#include <hip/hip_bf16.h>
#include <float.h>

#define N_CAT   100000
#define N_USERS 50000
#define N_REL   32
#define D       64
#define NEDGE   1600000
#define NNZ     1000000

#define EB_SHIFT 9
#define EB_SIZE  512
#define NBKE     ((N_CAT + EB_SIZE - 1) / EB_SIZE)    // 196 edge buckets
#define UB_SHIFT 8
#define UB_SIZE  256
#define NBKU     ((N_USERS + UB_SIZE - 1) / UB_SIZE)  // 196 user buckets
#define NBK      (NBKE + NBKU)                        // 392

#define T1   4096      // pass1 tile (16 recs/thread @ 256 threads)
#define ECAP 15360     // pass2 edge bucket LDS capacity (mean 8192, +79 sigma)
#define UCAP 7680      // pass2 user bucket LDS capacity (mean 5120, +36 sigma)

// ---------------------------------------------------------------------------
// ws: norm2[N_CAT*32] f32 | ccnt[392] | cbase_e[197] | cbase_u[197] |
//     ccur_e[196] | ccur_u[196] | offs_e[100001] | offs_u[50001] |
//     sorted_ta[NEDGE] int | sorted_cv[NNZ] int2      (~27.8 MB)
// ---------------------------------------------------------------------------

__global__ void norm2_kernel(const float* __restrict__ cat,
                             const float* __restrict__ W,
                             float* __restrict__ norm2) {
    int gid = blockIdx.x * blockDim.x + threadIdx.x;
    if (gid >= N_CAT * N_REL) return;
    int node = gid >> 5;
    int rel  = gid & 31;
    const float4* c = (const float4*)(cat + (size_t)node * D);
    const float4* w = (const float4*)(W + (size_t)rel * D);
    float s = 0.f;
#pragma unroll
    for (int i = 0; i < 16; ++i) {
        float4 a = c[i], b = w[i];
        float p0 = a.x * b.x, p1 = a.y * b.y, p2 = a.z * b.z, p3 = a.w * b.w;
        s += p0 * p0 + p1 * p1 + p2 * p2 + p3 * p3;
    }
    norm2[gid] = s;
}

// per-WG LDS histogram over 392 coarse buckets, single flush
__global__ void coarse_hist_kernel(const int* __restrict__ head,
                                   const int* __restrict__ imr,
                                   int* __restrict__ ccnt) {
    __shared__ int h[NBK];
    int t = threadIdx.x;
    for (int i = t; i < NBK; i += 256) h[i] = 0;
    __syncthreads();
    int stride = gridDim.x * 256;
    for (int i = blockIdx.x * 256 + t; i < NEDGE + NNZ; i += stride) {
        if (i < NEDGE) atomicAdd(&h[head[i] >> EB_SHIFT], 1);
        else           atomicAdd(&h[NBKE + (imr[i - NEDGE] >> UB_SHIFT)], 1);
    }
    __syncthreads();
    for (int i = t; i < NBK; i += 256) if (h[i]) atomicAdd(&ccnt[i], h[i]);
}

// single-WG scan of 392 coarse bins -> bucket bases + cursors + sentinels
__global__ void coarse_scan_kernel(const int* __restrict__ ccnt,
                                   int* __restrict__ cbase_e, int* __restrict__ cbase_u,
                                   int* __restrict__ ccur_e,  int* __restrict__ ccur_u,
                                   int* __restrict__ offs_e,  int* __restrict__ offs_u) {
    __shared__ int sc[256];
    int t = threadIdx.x;
    int c = (t < NBKE) ? ccnt[t] : 0;
    sc[t] = c; __syncthreads();
    for (int off = 1; off < 256; off <<= 1) {
        int v = (t >= off) ? sc[t - off] : 0; __syncthreads();
        sc[t] += v; __syncthreads();
    }
    int excl = sc[t] - c;
    if (t < NBKE) { cbase_e[t] = excl; ccur_e[t] = excl; }
    if (t == NBKE - 1) cbase_e[NBKE] = excl + c;
    __syncthreads();
    c = (t < NBKU) ? ccnt[NBKE + t] : 0;
    sc[t] = c; __syncthreads();
    for (int off = 1; off < 256; off <<= 1) {
        int v = (t >= off) ? sc[t - off] : 0; __syncthreads();
        sc[t] += v; __syncthreads();
    }
    excl = sc[t] - c;
    if (t < NBKU) { cbase_u[t] = excl; ccur_u[t] = excl; }
    if (t == NBKU - 1) cbase_u[NBKU] = excl + c;
    if (t == 0) { offs_e[N_CAT] = NEDGE; offs_u[N_USERS] = NNZ; }
}

// pass1 edges: tile -> LDS count/scan -> ONE global atomic per (tile,bucket)
// -> staged bucket-ordered write-out (coalesced runs)
__global__ __launch_bounds__(256) void pass1_edges_kernel(
        const int* __restrict__ head, const int* __restrict__ tail,
        const int* __restrict__ etype, int* __restrict__ ccur_e,
        int* __restrict__ sorted_ta) {
    __shared__ int cnt[256], loc[256], base[256], sc[256];
    __shared__ int stage[T1];
    __shared__ int gpos[T1];
    int t = threadIdx.x;
    int tile = blockIdx.x * T1;
    cnt[t] = 0;
    __syncthreads();
    int rec[16], bk[16];
#pragma unroll
    for (int k = 0; k < 16; ++k) {
        int i = tile + k * 256 + t;
        if (i < NEDGE) {
            int h = head[i], tl = tail[i], r = etype[i] - 1;
            bk[k]  = h >> EB_SHIFT;
            rec[k] = ((h & (EB_SIZE - 1)) << 22) | (tl << 5) | r;
            atomicAdd(&cnt[bk[k]], 1);
        } else bk[k] = -1;
    }
    __syncthreads();
    int c = cnt[t];
    sc[t] = c; __syncthreads();
    for (int off = 1; off < 256; off <<= 1) {
        int v = (t >= off) ? sc[t - off] : 0; __syncthreads();
        sc[t] += v; __syncthreads();
    }
    loc[t] = sc[t] - c;
    if (t < NBKE && c > 0) base[t] = atomicAdd(&ccur_e[t], c);
    __syncthreads();
    cnt[t] = loc[t];
    __syncthreads();
#pragma unroll
    for (int k = 0; k < 16; ++k) {
        if (bk[k] >= 0) {
            int p = atomicAdd(&cnt[bk[k]], 1);
            stage[p] = rec[k];
            gpos[p]  = base[bk[k]] + (p - loc[bk[k]]);
        }
    }
    __syncthreads();
    int nv = min(T1, NEDGE - tile);
    for (int i = t; i < nv; i += 256) sorted_ta[gpos[i]] = stage[i];
}

__global__ __launch_bounds__(256) void pass1_users_kernel(
        const int* __restrict__ imr, const int* __restrict__ imc,
        const float* __restrict__ imv, int* __restrict__ ccur_u,
        int2* __restrict__ sorted_cv) {
    __shared__ int cnt[256], loc[256], base[256], sc[256];
    __shared__ int2 stage[T1];
    __shared__ int gpos[T1];
    int t = threadIdx.x;
    int tile = blockIdx.x * T1;
    cnt[t] = 0;
    __syncthreads();
    int2 rec[16]; int bk[16];
#pragma unroll
    for (int k = 0; k < 16; ++k) {
        int i = tile + k * 256 + t;
        if (i < NNZ) {
            int rr = imr[i];
            bk[k]  = rr >> UB_SHIFT;
            rec[k] = make_int2(((rr & (UB_SIZE - 1)) << 17) | imc[i],
                               __float_as_int(imv[i]));
            atomicAdd(&cnt[bk[k]], 1);
        } else bk[k] = -1;
    }
    __syncthreads();
    int c = cnt[t];
    sc[t] = c; __syncthreads();
    for (int off = 1; off < 256; off <<= 1) {
        int v = (t >= off) ? sc[t - off] : 0; __syncthreads();
        sc[t] += v; __syncthreads();
    }
    loc[t] = sc[t] - c;
    if (t < NBKU && c > 0) base[t] = atomicAdd(&ccur_u[t], c);
    __syncthreads();
    cnt[t] = loc[t];
    __syncthreads();
#pragma unroll
    for (int k = 0; k < 16; ++k) {
        if (bk[k] >= 0) {
            int p = atomicAdd(&cnt[bk[k]], 1);
            stage[p] = rec[k];
            gpos[p]  = base[bk[k]] + (p - loc[bk[k]]);
        }
    }
    __syncthreads();
    int nv = min(T1, NNZ - tile);
    for (int i = t; i < nv; i += 256) sorted_cv[gpos[i]] = stage[i];
}

// pass2: one WG per coarse bucket; fine counting-sort in LDS; writes fine offs
__global__ __launch_bounds__(256) void pass2_kernel(
        const int* __restrict__ cbase_e, const int* __restrict__ cbase_u,
        int* __restrict__ offs_e, int* __restrict__ offs_u,
        int* __restrict__ sorted_ta, int2* __restrict__ sorted_cv) {
    __shared__ int lds[UCAP * 2];        // 60 KB, shared edge(int)/user(int2) stage
    __shared__ int fh[EB_SIZE + 1];
    __shared__ int sc[256];
    int t = threadIdx.x;
    int b = blockIdx.x;
    if (b < NBKE) {
        int h0 = b << EB_SHIFT;
        int start = cbase_e[b], end = cbase_e[b + 1];
        int n = min(end - start, ECAP);
        for (int i = t; i < n; i += 256) lds[i] = sorted_ta[start + i];
        fh[2 * t] = 0; fh[2 * t + 1] = 0;
        __syncthreads();
        for (int i = t; i < n; i += 256) atomicAdd(&fh[lds[i] >> 22], 1);
        __syncthreads();
        int a = fh[2 * t], b2 = fh[2 * t + 1];
        sc[t] = a + b2; __syncthreads();
        for (int off = 1; off < 256; off <<= 1) {
            int v = (t >= off) ? sc[t - off] : 0; __syncthreads();
            sc[t] += v; __syncthreads();
        }
        int pe = sc[t] - (a + b2);
        int lim = min(EB_SIZE, N_CAT - h0);
        if (2 * t     < lim) offs_e[h0 + 2 * t]     = start + pe;
        if (2 * t + 1 < lim) offs_e[h0 + 2 * t + 1] = start + pe + a;
        fh[2 * t] = pe; fh[2 * t + 1] = pe + a;
        __syncthreads();
        for (int i = t; i < n; i += 256) {
            int rec = lds[i];
            int p = atomicAdd(&fh[rec >> 22], 1);
            sorted_ta[start + p] = rec & 0x3FFFFF;     // (tail<<5)|rel
        }
    } else {
        int k = b - NBKE;
        int u0 = k << UB_SHIFT;
        int start = cbase_u[k], end = cbase_u[k + 1];
        int n = min(end - start, UCAP);
        int2* lds2 = (int2*)lds;
        for (int i = t; i < n; i += 256) lds2[i] = sorted_cv[start + i];
        fh[t] = 0;
        __syncthreads();
        for (int i = t; i < n; i += 256) atomicAdd(&fh[lds2[i].x >> 17], 1);
        __syncthreads();
        int c = fh[t];
        sc[t] = c; __syncthreads();
        for (int off = 1; off < 256; off <<= 1) {
            int v = (t >= off) ? sc[t - off] : 0; __syncthreads();
            sc[t] += v; __syncthreads();
        }
        int excl = sc[t] - c;
        int lim = min(UB_SIZE, N_USERS - u0);
        if (t < lim) offs_u[u0 + t] = start + excl;
        fh[t] = excl;
        __syncthreads();
        for (int i = t; i < n; i += 256) {
            int2 rec = lds2[i];
            int p = atomicAdd(&fh[rec.x >> 17], 1);
            sorted_cv[start + p] = make_int2(rec.x & 0x1FFFF, rec.y);
        }
    }
}

// one wave per head; fast path deg<=64: single record read, softmax in registers
__global__ void cat_agg_sorted_kernel(const int* __restrict__ offs_e,
                                      const int* __restrict__ sorted_ta,
                                      const float* __restrict__ norm2,
                                      const float* __restrict__ cat,
                                      const float* __restrict__ W,
                                      float* __restrict__ cat_agg) {
    int wv   = threadIdx.x >> 6;
    int lane = threadIdx.x & 63;
    int h = blockIdx.x * 4 + wv;
    int start = offs_e[h];
    int end   = offs_e[h + 1];
    int deg   = end - start;

    float a0 = 0.f, a1 = 0.f, a2 = 0.f, a3 = 0.f;

    if (deg <= 64) {
        int   rec = 0;
        float att = -FLT_MAX;
        if (lane < deg) {
            rec = sorted_ta[start + lane];
            int tt = rec >> 5, r = rec & 31;
            att = norm2[h * N_REL + r] * norm2[(size_t)tt * N_REL + r];
        }
        float m = att;
#pragma unroll
        for (int off = 32; off > 0; off >>= 1) m = fmaxf(m, __shfl_xor(m, off));
        float ex = (lane < deg) ? __expf(att - m) : 0.f;
        float ssum = ex;
#pragma unroll
        for (int off = 32; off > 0; off >>= 1) ssum += __shfl_xor(ssum, off);
        float w = (deg > 0) ? ex / ssum : 0.f;

        int j = 0;
        for (; j + 4 <= deg; j += 4) {
            int   tr0 = __shfl(rec, j + 0), tr1 = __shfl(rec, j + 1);
            int   tr2 = __shfl(rec, j + 2), tr3 = __shfl(rec, j + 3);
            float w0  = __shfl(w,   j + 0), w1  = __shfl(w,   j + 1);
            float w2  = __shfl(w,   j + 2), w3  = __shfl(w,   j + 3);
            a0 += w0 * cat[(size_t)(tr0 >> 5) * D + lane] * W[(tr0 & 31) * D + lane];
            a1 += w1 * cat[(size_t)(tr1 >> 5) * D + lane] * W[(tr1 & 31) * D + lane];
            a2 += w2 * cat[(size_t)(tr2 >> 5) * D + lane] * W[(tr2 & 31) * D + lane];
            a3 += w3 * cat[(size_t)(tr3 >> 5) * D + lane] * W[(tr3 & 31) * D + lane];
        }
        for (; j < deg; ++j) {
            int   tr = __shfl(rec, j);
            float ww = __shfl(w,   j);
            a0 += ww * cat[(size_t)(tr >> 5) * D + lane] * W[(tr & 31) * D + lane];
        }
    } else {
        float m = -FLT_MAX;
        for (int j = lane; j < deg; j += 64) {
            int rec = sorted_ta[start + j];
            int tt = rec >> 5, r = rec & 31;
            m = fmaxf(m, norm2[h * N_REL + r] * norm2[(size_t)tt * N_REL + r]);
        }
#pragma unroll
        for (int off = 32; off > 0; off >>= 1) m = fmaxf(m, __shfl_xor(m, off));
        float ssum = 0.f;
        for (int j = lane; j < deg; j += 64) {
            int rec = sorted_ta[start + j];
            int tt = rec >> 5, r = rec & 31;
            ssum += __expf(norm2[h * N_REL + r] * norm2[(size_t)tt * N_REL + r] - m);
        }
#pragma unroll
        for (int off = 32; off > 0; off >>= 1) ssum += __shfl_xor(ssum, off);
        float inv = 1.f / ssum;
        for (int j0 = 0; j0 < deg; j0 += 64) {
            int n = min(64, deg - j0);
            int   rec = 0;
            float w   = 0.f;
            if (lane < n) {
                rec = sorted_ta[start + j0 + lane];
                int tt = rec >> 5, r = rec & 31;
                w = __expf(norm2[h * N_REL + r] * norm2[(size_t)tt * N_REL + r] - m) * inv;
            }
            for (int j = 0; j < n; ++j) {
                int   tr = __shfl(rec, j);
                float ww = __shfl(w,   j);
                a0 += ww * cat[(size_t)(tr >> 5) * D + lane] * W[(tr & 31) * D + lane];
            }
        }
    }
    cat_agg[(size_t)h * D + lane] = (a0 + a1) + (a2 + a3);
}

__global__ void spmm_user_kernel(const int* __restrict__ offs_u,
                                 const int2* __restrict__ sorted_cv,
                                 const float* __restrict__ cat,
                                 const float* __restrict__ uemb,
                                 const float* __restrict__ W,
                                 float* __restrict__ uagg) {
    __shared__ float s_user[4][D];
    __shared__ float s_score[4][N_REL];
    int wv   = threadIdx.x >> 6;
    int lane = threadIdx.x & 63;
    int u = blockIdx.x * 4 + wv;
    int start = offs_u[u];
    int end   = offs_u[u + 1];
    int deg   = end - start;

    float a0 = 0.f, a1 = 0.f, a2 = 0.f, a3 = 0.f;
    for (int j0 = 0; j0 < deg; j0 += 64) {
        int n = min(64, deg - j0);
        int   my_c = 0;
        float my_v = 0.f;
        if (lane < n) {
            int2 cv = sorted_cv[start + j0 + lane];
            my_c = cv.x;
            my_v = __int_as_float(cv.y);
        }
        int j = 0;
        for (; j + 4 <= n; j += 4) {
            int   c0 = __shfl(my_c, j + 0), c1 = __shfl(my_c, j + 1);
            int   c2 = __shfl(my_c, j + 2), c3 = __shfl(my_c, j + 3);
            float v0 = __shfl(my_v, j + 0), v1 = __shfl(my_v, j + 1);
            float v2 = __shfl(my_v, j + 2), v3 = __shfl(my_v, j + 3);
            a0 += v0 * cat[(size_t)c0 * D + lane];
            a1 += v1 * cat[(size_t)c1 * D + lane];
            a2 += v2 * cat[(size_t)c2 * D + lane];
            a3 += v3 * cat[(size_t)c3 * D + lane];
        }
        for (; j < n; ++j) {
            int   cc = __shfl(my_c, j);
            float vv = __shfl(my_v, j);
            a0 += vv * cat[(size_t)cc * D + lane];
        }
    }
    float acc = (a0 + a1) + (a2 + a3);

    s_user[wv][lane] = uemb[(size_t)u * D + lane];
    __syncthreads();

    if (lane < N_REL) {
        float dot = 0.f;
#pragma unroll
        for (int d = 0; d < D; ++d) dot += s_user[wv][d] * W[lane * D + d];
        float mm = dot;
#pragma unroll
        for (int off = 16; off > 0; off >>= 1) mm = fmaxf(mm, __shfl_xor(mm, off));
        float ex = __expf(dot - mm);
        float sm = ex;
#pragma unroll
        for (int off = 16; off > 0; off >>= 1) sm += __shfl_xor(sm, off);
        s_score[wv][lane] = ex / sm;
    }
    __syncthreads();

    float proj = 0.f;
#pragma unroll
    for (int r = 0; r < N_REL; ++r) proj += s_score[wv][r] * W[r * D + lane];

    uagg[(size_t)u * D + lane] = acc * (1.f + proj);
}

extern "C" void kernel_launch(void* const* d_in, const int* in_sizes, int n_in,
                              void* d_out, int out_size, void* d_ws, size_t ws_size,
                              hipStream_t stream) {
    const float* cat   = (const float*)d_in[0];
    const float* uemb  = (const float*)d_in[1];
    const int*   eidx  = (const int*)d_in[2];
    const int*   etype = (const int*)d_in[3];
    const int*   imr   = (const int*)d_in[4];
    const int*   imc   = (const int*)d_in[5];
    const float* imv   = (const float*)d_in[6];
    const float* W     = (const float*)d_in[7];
    const int* head = eidx;
    const int* tail = eidx + NEDGE;

    float* out     = (float*)d_out;
    float* cat_agg = out;                         // [N_CAT, D]
    float* uagg    = out + (size_t)N_CAT * D;     // [N_USERS, D]

    float* norm2   = (float*)d_ws;
    int*   ccnt    = (int*)(norm2 + (size_t)N_CAT * N_REL);
    int*   cbase_e = ccnt + NBK;
    int*   cbase_u = cbase_e + NBKE + 1;
    int*   ccur_e  = cbase_u + NBKU + 1;
    int*   ccur_u  = ccur_e + NBKE;
    int*   offs_e  = ccur_u + NBKU;
    int*   offs_u  = offs_e + N_CAT + 1;
    int*   sorted_ta = offs_u + N_USERS + 1;
    int2*  sorted_cv = (int2*)(sorted_ta + NEDGE);   // offset sums to even -> 8B aligned

    hipMemsetAsync(ccnt, 0, (size_t)NBK * sizeof(int), stream);

    coarse_hist_kernel<<<512, 256, 0, stream>>>(head, imr, ccnt);
    coarse_scan_kernel<<<1, 256, 0, stream>>>(ccnt, cbase_e, cbase_u,
                                              ccur_e, ccur_u, offs_e, offs_u);
    pass1_edges_kernel<<<(NEDGE + T1 - 1) / T1, 256, 0, stream>>>(
        head, tail, etype, ccur_e, sorted_ta);
    pass1_users_kernel<<<(NNZ + T1 - 1) / T1, 256, 0, stream>>>(
        imr, imc, imv, ccur_u, sorted_cv);
    pass2_kernel<<<NBK, 256, 0, stream>>>(cbase_e, cbase_u, offs_e, offs_u,
                                          sorted_ta, sorted_cv);
    norm2_kernel<<<(N_CAT * N_REL + 255) / 256, 256, 0, stream>>>(cat, W, norm2);
    cat_agg_sorted_kernel<<<N_CAT / 4, 256, 0, stream>>>(offs_e, sorted_ta, norm2, cat, W, cat_agg);
    spmm_user_kernel<<<N_USERS / 4, 256, 0, stream>>>(offs_u, sorted_cv, cat, uemb, W, uagg);
}

// Round 6
// 459.594 us; speedup vs baseline: 2.1670x; 1.0062x over previous
//
#include <hip/hip_runtime.h>
#include <hip/hip_bf16.h>
#include <float.h>

#define N_CAT   100000
#define N_USERS 50000
#define N_REL   32
#define D       64
#define NEDGE   1600000
#define NNZ     1000000

#define EB_SHIFT 9
#define EB_SIZE  512
#define NBKE     ((N_CAT + EB_SIZE - 1) / EB_SIZE)    // 196 edge buckets
#define UB_SHIFT 8
#define UB_SIZE  256
#define NBKU     ((N_USERS + UB_SIZE - 1) / UB_SIZE)  // 196 user buckets
#define NBK      (NBKE + NBKU)                        // 392

#define T1   4096      // pass1 tile (16 recs/thread @ 256 threads)
#define ECAP 15360     // pass2 edge bucket LDS capacity
#define UCAP 7680      // pass2 user bucket LDS capacity

#define NB2  ((N_CAT + 255) / 256)   // norm2 GEMM blocks (391)
#define XPAD 17                      // xs row pitch in float4 (68 floats)

// ---------------------------------------------------------------------------
// ws: norm2[N_CAT*32] f32 | ccnt[392] | cbase_e[197] | cbase_u[197] |
//     ccur_e[196] | ccur_u[196] | offs_e[100001] | offs_u[50001] |
//     sorted_ta[NEDGE] int | sorted_cv[NNZ] int2      (~27.8 MB)
// ---------------------------------------------------------------------------

// norm2 = (cat^2) @ (W^2)^T as an LDS-tiled register-blocked vector GEMM.
// Block: 256 rows of cat staged squared into LDS (row pitch 68 floats) +
// squared W (8 KB). Thread tile: 8 nodes (stride 32) x 4 rels.
__global__ __launch_bounds__(256) void norm2_kernel(
        const float* __restrict__ cat,
        const float* __restrict__ W,
        float* __restrict__ norm2) {
    __shared__ float4 xs[256 * XPAD];     // 68 KB (padded rows)
    __shared__ float4 w2[N_REL * 16];     // 8 KB
    int t  = threadIdx.x;
    int n0 = blockIdx.x * 256;

    // stage squared cat rows, coalesced
    const float4* catv = (const float4*)cat;
#pragma unroll
    for (int i = 0; i < 16; ++i) {
        int li = t + i * 256;                 // linear float4 idx within block
        int g  = n0 * 16 + li;
        float4 v = make_float4(0.f, 0.f, 0.f, 0.f);
        if (g < N_CAT * 16) v = catv[g];
        v.x *= v.x; v.y *= v.y; v.z *= v.z; v.w *= v.w;
        xs[(li >> 4) * XPAD + (li & 15)] = v;
    }
    // stage squared W
    const float4* Wv = (const float4*)W;
    for (int i = t; i < N_REL * 16; i += 256) {
        float4 v = Wv[i];
        v.x *= v.x; v.y *= v.y; v.z *= v.z; v.w *= v.w;
        w2[i] = v;
    }
    __syncthreads();

    int ng = t & 31;          // node within group-of-32
    int rg = t >> 5;          // rel group (4 rels): 0..7
    float acc[8][4];
#pragma unroll
    for (int k = 0; k < 8; ++k)
#pragma unroll
        for (int j = 0; j < 4; ++j) acc[k][j] = 0.f;

#pragma unroll
    for (int c = 0; c < 16; ++c) {
        float4 wv0 = w2[(rg * 4 + 0) * 16 + c];
        float4 wv1 = w2[(rg * 4 + 1) * 16 + c];
        float4 wv2 = w2[(rg * 4 + 2) * 16 + c];
        float4 wv3 = w2[(rg * 4 + 3) * 16 + c];
#pragma unroll
        for (int k = 0; k < 8; ++k) {
            float4 xv = xs[(k * 32 + ng) * XPAD + c];
            acc[k][0] += xv.x * wv0.x + xv.y * wv0.y + xv.z * wv0.z + xv.w * wv0.w;
            acc[k][1] += xv.x * wv1.x + xv.y * wv1.y + xv.z * wv1.z + xv.w * wv1.w;
            acc[k][2] += xv.x * wv2.x + xv.y * wv2.y + xv.z * wv2.z + xv.w * wv2.w;
            acc[k][3] += xv.x * wv3.x + xv.y * wv3.y + xv.z * wv3.z + xv.w * wv3.w;
        }
    }

    float4* nv = (float4*)norm2;          // 8 float4 per node row of 32 rels
#pragma unroll
    for (int k = 0; k < 8; ++k) {
        int node = n0 + k * 32 + ng;
        if (node < N_CAT)
            nv[(size_t)node * 8 + rg] = make_float4(acc[k][0], acc[k][1],
                                                    acc[k][2], acc[k][3]);
    }
}

// per-WG LDS histogram over 392 coarse buckets, single flush
__global__ void coarse_hist_kernel(const int* __restrict__ head,
                                   const int* __restrict__ imr,
                                   int* __restrict__ ccnt) {
    __shared__ int h[NBK];
    int t = threadIdx.x;
    for (int i = t; i < NBK; i += 256) h[i] = 0;
    __syncthreads();
    int stride = gridDim.x * 256;
    for (int i = blockIdx.x * 256 + t; i < NEDGE + NNZ; i += stride) {
        if (i < NEDGE) atomicAdd(&h[head[i] >> EB_SHIFT], 1);
        else           atomicAdd(&h[NBKE + (imr[i - NEDGE] >> UB_SHIFT)], 1);
    }
    __syncthreads();
    for (int i = t; i < NBK; i += 256) if (h[i]) atomicAdd(&ccnt[i], h[i]);
}

// single-WG scan of 392 coarse bins -> bucket bases + cursors + sentinels
__global__ void coarse_scan_kernel(const int* __restrict__ ccnt,
                                   int* __restrict__ cbase_e, int* __restrict__ cbase_u,
                                   int* __restrict__ ccur_e,  int* __restrict__ ccur_u,
                                   int* __restrict__ offs_e,  int* __restrict__ offs_u) {
    __shared__ int sc[256];
    int t = threadIdx.x;
    int c = (t < NBKE) ? ccnt[t] : 0;
    sc[t] = c; __syncthreads();
    for (int off = 1; off < 256; off <<= 1) {
        int v = (t >= off) ? sc[t - off] : 0; __syncthreads();
        sc[t] += v; __syncthreads();
    }
    int excl = sc[t] - c;
    if (t < NBKE) { cbase_e[t] = excl; ccur_e[t] = excl; }
    if (t == NBKE - 1) cbase_e[NBKE] = excl + c;
    __syncthreads();
    c = (t < NBKU) ? ccnt[NBKE + t] : 0;
    sc[t] = c; __syncthreads();
    for (int off = 1; off < 256; off <<= 1) {
        int v = (t >= off) ? sc[t - off] : 0; __syncthreads();
        sc[t] += v; __syncthreads();
    }
    excl = sc[t] - c;
    if (t < NBKU) { cbase_u[t] = excl; ccur_u[t] = excl; }
    if (t == NBKU - 1) cbase_u[NBKU] = excl + c;
    if (t == 0) { offs_e[N_CAT] = NEDGE; offs_u[N_USERS] = NNZ; }
}

// pass1 edges: tile -> LDS count/scan -> ONE global atomic per (tile,bucket)
__global__ __launch_bounds__(256) void pass1_edges_kernel(
        const int* __restrict__ head, const int* __restrict__ tail,
        const int* __restrict__ etype, int* __restrict__ ccur_e,
        int* __restrict__ sorted_ta) {
    __shared__ int cnt[256], loc[256], base[256], sc[256];
    __shared__ int stage[T1];
    __shared__ int gpos[T1];
    int t = threadIdx.x;
    int tile = blockIdx.x * T1;
    cnt[t] = 0;
    __syncthreads();
    int rec[16], bk[16];
#pragma unroll
    for (int k = 0; k < 16; ++k) {
        int i = tile + k * 256 + t;
        if (i < NEDGE) {
            int h = head[i], tl = tail[i], r = etype[i] - 1;
            bk[k]  = h >> EB_SHIFT;
            rec[k] = ((h & (EB_SIZE - 1)) << 22) | (tl << 5) | r;
            atomicAdd(&cnt[bk[k]], 1);
        } else bk[k] = -1;
    }
    __syncthreads();
    int c = cnt[t];
    sc[t] = c; __syncthreads();
    for (int off = 1; off < 256; off <<= 1) {
        int v = (t >= off) ? sc[t - off] : 0; __syncthreads();
        sc[t] += v; __syncthreads();
    }
    loc[t] = sc[t] - c;
    if (t < NBKE && c > 0) base[t] = atomicAdd(&ccur_e[t], c);
    __syncthreads();
    cnt[t] = loc[t];
    __syncthreads();
#pragma unroll
    for (int k = 0; k < 16; ++k) {
        if (bk[k] >= 0) {
            int p = atomicAdd(&cnt[bk[k]], 1);
            stage[p] = rec[k];
            gpos[p]  = base[bk[k]] + (p - loc[bk[k]]);
        }
    }
    __syncthreads();
    int nv = min(T1, NEDGE - tile);
    for (int i = t; i < nv; i += 256) sorted_ta[gpos[i]] = stage[i];
}

__global__ __launch_bounds__(256) void pass1_users_kernel(
        const int* __restrict__ imr, const int* __restrict__ imc,
        const float* __restrict__ imv, int* __restrict__ ccur_u,
        int2* __restrict__ sorted_cv) {
    __shared__ int cnt[256], loc[256], base[256], sc[256];
    __shared__ int2 stage[T1];
    __shared__ int gpos[T1];
    int t = threadIdx.x;
    int tile = blockIdx.x * T1;
    cnt[t] = 0;
    __syncthreads();
    int2 rec[16]; int bk[16];
#pragma unroll
    for (int k = 0; k < 16; ++k) {
        int i = tile + k * 256 + t;
        if (i < NNZ) {
            int rr = imr[i];
            bk[k]  = rr >> UB_SHIFT;
            rec[k] = make_int2(((rr & (UB_SIZE - 1)) << 17) | imc[i],
                               __float_as_int(imv[i]));
            atomicAdd(&cnt[bk[k]], 1);
        } else bk[k] = -1;
    }
    __syncthreads();
    int c = cnt[t];
    sc[t] = c; __syncthreads();
    for (int off = 1; off < 256; off <<= 1) {
        int v = (t >= off) ? sc[t - off] : 0; __syncthreads();
        sc[t] += v; __syncthreads();
    }
    loc[t] = sc[t] - c;
    if (t < NBKU && c > 0) base[t] = atomicAdd(&ccur_u[t], c);
    __syncthreads();
    cnt[t] = loc[t];
    __syncthreads();
#pragma unroll
    for (int k = 0; k < 16; ++k) {
        if (bk[k] >= 0) {
            int p = atomicAdd(&cnt[bk[k]], 1);
            stage[p] = rec[k];
            gpos[p]  = base[bk[k]] + (p - loc[bk[k]]);
        }
    }
    __syncthreads();
    int nv = min(T1, NNZ - tile);
    for (int i = t; i < nv; i += 256) sorted_cv[gpos[i]] = stage[i];
}

// pass2: one WG per coarse bucket; fine counting-sort in LDS; writes fine offs
__global__ __launch_bounds__(256) void pass2_kernel(
        const int* __restrict__ cbase_e, const int* __restrict__ cbase_u,
        int* __restrict__ offs_e, int* __restrict__ offs_u,
        int* __restrict__ sorted_ta, int2* __restrict__ sorted_cv) {
    __shared__ int lds[UCAP * 2];        // 60 KB
    __shared__ int fh[EB_SIZE + 1];
    __shared__ int sc[256];
    int t = threadIdx.x;
    int b = blockIdx.x;
    if (b < NBKE) {
        int h0 = b << EB_SHIFT;
        int start = cbase_e[b], end = cbase_e[b + 1];
        int n = min(end - start, ECAP);
        for (int i = t; i < n; i += 256) lds[i] = sorted_ta[start + i];
        fh[2 * t] = 0; fh[2 * t + 1] = 0;
        __syncthreads();
        for (int i = t; i < n; i += 256) atomicAdd(&fh[lds[i] >> 22], 1);
        __syncthreads();
        int a = fh[2 * t], b2 = fh[2 * t + 1];
        sc[t] = a + b2; __syncthreads();
        for (int off = 1; off < 256; off <<= 1) {
            int v = (t >= off) ? sc[t - off] : 0; __syncthreads();
            sc[t] += v; __syncthreads();
        }
        int pe = sc[t] - (a + b2);
        int lim = min(EB_SIZE, N_CAT - h0);
        if (2 * t     < lim) offs_e[h0 + 2 * t]     = start + pe;
        if (2 * t + 1 < lim) offs_e[h0 + 2 * t + 1] = start + pe + a;
        fh[2 * t] = pe; fh[2 * t + 1] = pe + a;
        __syncthreads();
        for (int i = t; i < n; i += 256) {
            int rec = lds[i];
            int p = atomicAdd(&fh[rec >> 22], 1);
            sorted_ta[start + p] = rec & 0x3FFFFF;     // (tail<<5)|rel
        }
    } else {
        int k = b - NBKE;
        int u0 = k << UB_SHIFT;
        int start = cbase_u[k], end = cbase_u[k + 1];
        int n = min(end - start, UCAP);
        int2* lds2 = (int2*)lds;
        for (int i = t; i < n; i += 256) lds2[i] = sorted_cv[start + i];
        fh[t] = 0;
        __syncthreads();
        for (int i = t; i < n; i += 256) atomicAdd(&fh[lds2[i].x >> 17], 1);
        __syncthreads();
        int c = fh[t];
        sc[t] = c; __syncthreads();
        for (int off = 1; off < 256; off <<= 1) {
            int v = (t >= off) ? sc[t - off] : 0; __syncthreads();
            sc[t] += v; __syncthreads();
        }
        int excl = sc[t] - c;
        int lim = min(UB_SIZE, N_USERS - u0);
        if (t < lim) offs_u[u0 + t] = start + excl;
        fh[t] = excl;
        __syncthreads();
        for (int i = t; i < n; i += 256) {
            int2 rec = lds2[i];
            int p = atomicAdd(&fh[rec.x >> 17], 1);
            sorted_cv[start + p] = make_int2(rec.x & 0x1FFFF, rec.y);
        }
    }
}

// one wave per head; fast path deg<=64: single record read, softmax in registers
__global__ void cat_agg_sorted_kernel(const int* __restrict__ offs_e,
                                      const int* __restrict__ sorted_ta,
                                      const float* __restrict__ norm2,
                                      const float* __restrict__ cat,
                                      const float* __restrict__ W,
                                      float* __restrict__ cat_agg) {
    int wv   = threadIdx.x >> 6;
    int lane = threadIdx.x & 63;
    int h = blockIdx.x * 4 + wv;
    int start = offs_e[h];
    int end   = offs_e[h + 1];
    int deg   = end - start;

    float a0 = 0.f, a1 = 0.f, a2 = 0.f, a3 = 0.f;

    if (deg <= 64) {
        int   rec = 0;
        float att = -FLT_MAX;
        if (lane < deg) {
            rec = sorted_ta[start + lane];
            int tt = rec >> 5, r = rec & 31;
            att = norm2[h * N_REL + r] * norm2[(size_t)tt * N_REL + r];
        }
        float m = att;
#pragma unroll
        for (int off = 32; off > 0; off >>= 1) m = fmaxf(m, __shfl_xor(m, off));
        float ex = (lane < deg) ? __expf(att - m) : 0.f;
        float ssum = ex;
#pragma unroll
        for (int off = 32; off > 0; off >>= 1) ssum += __shfl_xor(ssum, off);
        float w = (deg > 0) ? ex / ssum : 0.f;

        int j = 0;
        for (; j + 4 <= deg; j += 4) {
            int   tr0 = __shfl(rec, j + 0), tr1 = __shfl(rec, j + 1);
            int   tr2 = __shfl(rec, j + 2), tr3 = __shfl(rec, j + 3);
            float w0  = __shfl(w,   j + 0), w1  = __shfl(w,   j + 1);
            float w2  = __shfl(w,   j + 2), w3  = __shfl(w,   j + 3);
            a0 += w0 * cat[(size_t)(tr0 >> 5) * D + lane] * W[(tr0 & 31) * D + lane];
            a1 += w1 * cat[(size_t)(tr1 >> 5) * D + lane] * W[(tr1 & 31) * D + lane];
            a2 += w2 * cat[(size_t)(tr2 >> 5) * D + lane] * W[(tr2 & 31) * D + lane];
            a3 += w3 * cat[(size_t)(tr3 >> 5) * D + lane] * W[(tr3 & 31) * D + lane];
        }
        for (; j < deg; ++j) {
            int   tr = __shfl(rec, j);
            float ww = __shfl(w,   j);
            a0 += ww * cat[(size_t)(tr >> 5) * D + lane] * W[(tr & 31) * D + lane];
        }
    } else {
        float m = -FLT_MAX;
        for (int j = lane; j < deg; j += 64) {
            int rec = sorted_ta[start + j];
            int tt = rec >> 5, r = rec & 31;
            m = fmaxf(m, norm2[h * N_REL + r] * norm2[(size_t)tt * N_REL + r]);
        }
#pragma unroll
        for (int off = 32; off > 0; off >>= 1) m = fmaxf(m, __shfl_xor(m, off));
        float ssum = 0.f;
        for (int j = lane; j < deg; j += 64) {
            int rec = sorted_ta[start + j];
            int tt = rec >> 5, r = rec & 31;
            ssum += __expf(norm2[h * N_REL + r] * norm2[(size_t)tt * N_REL + r] - m);
        }
#pragma unroll
        for (int off = 32; off > 0; off >>= 1) ssum += __shfl_xor(ssum, off);
        float inv = 1.f / ssum;
        for (int j0 = 0; j0 < deg; j0 += 64) {
            int n = min(64, deg - j0);
            int   rec = 0;
            float w   = 0.f;
            if (lane < n) {
                rec = sorted_ta[start + j0 + lane];
                int tt = rec >> 5, r = rec & 31;
                w = __expf(norm2[h * N_REL + r] * norm2[(size_t)tt * N_REL + r] - m) * inv;
            }
            for (int j = 0; j < n; ++j) {
                int   tr = __shfl(rec, j);
                float ww = __shfl(w,   j);
                a0 += ww * cat[(size_t)(tr >> 5) * D + lane] * W[(tr & 31) * D + lane];
            }
        }
    }
    cat_agg[(size_t)h * D + lane] = (a0 + a1) + (a2 + a3);
}

__global__ void spmm_user_kernel(const int* __restrict__ offs_u,
                                 const int2* __restrict__ sorted_cv,
                                 const float* __restrict__ cat,
                                 const float* __restrict__ uemb,
                                 const float* __restrict__ W,
                                 float* __restrict__ uagg) {
    __shared__ float s_user[4][D];
    __shared__ float s_score[4][N_REL];
    int wv   = threadIdx.x >> 6;
    int lane = threadIdx.x & 63;
    int u = blockIdx.x * 4 + wv;
    int start = offs_u[u];
    int end   = offs_u[u + 1];
    int deg   = end - start;

    float a0 = 0.f, a1 = 0.f, a2 = 0.f, a3 = 0.f;
    for (int j0 = 0; j0 < deg; j0 += 64) {
        int n = min(64, deg - j0);
        int   my_c = 0;
        float my_v = 0.f;
        if (lane < n) {
            int2 cv = sorted_cv[start + j0 + lane];
            my_c = cv.x;
            my_v = __int_as_float(cv.y);
        }
        int j = 0;
        for (; j + 4 <= n; j += 4) {
            int   c0 = __shfl(my_c, j + 0), c1 = __shfl(my_c, j + 1);
            int   c2 = __shfl(my_c, j + 2), c3 = __shfl(my_c, j + 3);
            float v0 = __shfl(my_v, j + 0), v1 = __shfl(my_v, j + 1);
            float v2 = __shfl(my_v, j + 2), v3 = __shfl(my_v, j + 3);
            a0 += v0 * cat[(size_t)c0 * D + lane];
            a1 += v1 * cat[(size_t)c1 * D + lane];
            a2 += v2 * cat[(size_t)c2 * D + lane];
            a3 += v3 * cat[(size_t)c3 * D + lane];
        }
        for (; j < n; ++j) {
            int   cc = __shfl(my_c, j);
            float vv = __shfl(my_v, j);
            a0 += vv * cat[(size_t)cc * D + lane];
        }
    }
    float acc = (a0 + a1) + (a2 + a3);

    s_user[wv][lane] = uemb[(size_t)u * D + lane];
    __syncthreads();

    if (lane < N_REL) {
        float dot = 0.f;
#pragma unroll
        for (int d = 0; d < D; ++d) dot += s_user[wv][d] * W[lane * D + d];
        float mm = dot;
#pragma unroll
        for (int off = 16; off > 0; off >>= 1) mm = fmaxf(mm, __shfl_xor(mm, off));
        float ex = __expf(dot - mm);
        float sm = ex;
#pragma unroll
        for (int off = 16; off > 0; off >>= 1) sm += __shfl_xor(sm, off);
        s_score[wv][lane] = ex / sm;
    }
    __syncthreads();

    float proj = 0.f;
#pragma unroll
    for (int r = 0; r < N_REL; ++r) proj += s_score[wv][r] * W[r * D + lane];

    uagg[(size_t)u * D + lane] = acc * (1.f + proj);
}

extern "C" void kernel_launch(void* const* d_in, const int* in_sizes, int n_in,
                              void* d_out, int out_size, void* d_ws, size_t ws_size,
                              hipStream_t stream) {
    const float* cat   = (const float*)d_in[0];
    const float* uemb  = (const float*)d_in[1];
    const int*   eidx  = (const int*)d_in[2];
    const int*   etype = (const int*)d_in[3];
    const int*   imr   = (const int*)d_in[4];
    const int*   imc   = (const int*)d_in[5];
    const float* imv   = (const float*)d_in[6];
    const float* W     = (const float*)d_in[7];
    const int* head = eidx;
    const int* tail = eidx + NEDGE;

    float* out     = (float*)d_out;
    float* cat_agg = out;                         // [N_CAT, D]
    float* uagg    = out + (size_t)N_CAT * D;     // [N_USERS, D]

    float* norm2   = (float*)d_ws;
    int*   ccnt    = (int*)(norm2 + (size_t)N_CAT * N_REL);
    int*   cbase_e = ccnt + NBK;
    int*   cbase_u = cbase_e + NBKE + 1;
    int*   ccur_e  = cbase_u + NBKU + 1;
    int*   ccur_u  = ccur_e + NBKE;
    int*   offs_e  = ccur_u + NBKU;
    int*   offs_u  = offs_e + N_CAT + 1;
    int*   sorted_ta = offs_u + N_USERS + 1;
    int2*  sorted_cv = (int2*)(sorted_ta + NEDGE);

    hipMemsetAsync(ccnt, 0, (size_t)NBK * sizeof(int), stream);

    coarse_hist_kernel<<<512, 256, 0, stream>>>(head, imr, ccnt);
    coarse_scan_kernel<<<1, 256, 0, stream>>>(ccnt, cbase_e, cbase_u,
                                              ccur_e, ccur_u, offs_e, offs_u);
    pass1_edges_kernel<<<(NEDGE + T1 - 1) / T1, 256, 0, stream>>>(
        head, tail, etype, ccur_e, sorted_ta);
    pass1_users_kernel<<<(NNZ + T1 - 1) / T1, 256, 0, stream>>>(
        imr, imc, imv, ccur_u, sorted_cv);
    pass2_kernel<<<NBK, 256, 0, stream>>>(cbase_e, cbase_u, offs_e, offs_u,
                                          sorted_ta, sorted_cv);
    norm2_kernel<<<NB2, 256, 0, stream>>>(cat, W, norm2);
    cat_agg_sorted_kernel<<<N_CAT / 4, 256, 0, stream>>>(offs_e, sorted_ta, norm2, cat, W, cat_agg);
    spmm_user_kernel<<<N_USERS / 4, 256, 0, stream>>>(offs_u, sorted_cv, cat, uemb, W, uagg);
}

// Round 7
// 374.788 us; speedup vs baseline: 2.6574x; 1.2263x over previous
//
#include <hip/hip_runtime.h>
#include <hip/hip_bf16.h>
#include <float.h>

#define N_CAT   100000
#define N_USERS 50000
#define N_REL   32
#define D       64
#define NEDGE   1600000
#define NNZ     1000000

#define EB_SHIFT 9
#define EB_SIZE  512
#define NBKE     ((N_CAT + EB_SIZE - 1) / EB_SIZE)    // 196 edge buckets
#define UB_SHIFT 8
#define UB_SIZE  256
#define NBKU     ((N_USERS + UB_SIZE - 1) / UB_SIZE)  // 196 user buckets
#define NBK      (NBKE + NBKU)                        // 392

#define T1   4096      // pass1 tile (16 recs/thread @ 256 threads)
#define ECAP 15360     // pass2 edge bucket LDS capacity
#define UCAP 7680      // pass2 user bucket LDS capacity

// ---------------------------------------------------------------------------
// ws: norm2[N_CAT*32] f32 | ccnt[392] | cbase_e[197] | cbase_u[197] |
//     ccur_e[196] | ccur_u[196] | offs_e[100001] | offs_u[50001] |
//     sorted_ta[NEDGE] int | sorted_cv[NNZ] int2      (~27.8 MB)
// ---------------------------------------------------------------------------

// norm2[n][r] = sum_d cat[n][d]^2 * W[r][d]^2.
// 4 threads/node (16 dims each), W^2 in 8 KB LDS, 32 accs/thread (~55 VGPR,
// no spill -- round-6 version hit 256 VGPR + scratch spill + 8% occupancy),
// quad-reduce via 2x shfl_xor, constant-index stores.
__global__ __launch_bounds__(256) void norm2_kernel(
        const float* __restrict__ cat,
        const float* __restrict__ W,
        float* __restrict__ norm2) {
    __shared__ float4 w2[N_REL * 16];   // squared W, 8 KB
    int t = threadIdx.x;
    const float4* Wv = (const float4*)W;
    for (int i = t; i < N_REL * 16; i += 256) {
        float4 v = Wv[i];
        v.x *= v.x; v.y *= v.y; v.z *= v.z; v.w *= v.w;
        w2[i] = v;
    }
    __syncthreads();

    int node = blockIdx.x * 64 + (t >> 2);
    int q    = t & 3;                     // which 16-dim quarter
    if (node >= N_CAT) return;

    const float4* catv = (const float4*)cat;
    float acc[N_REL];
#pragma unroll
    for (int r = 0; r < N_REL; ++r) acc[r] = 0.f;

#pragma unroll
    for (int c = 0; c < 4; ++c) {
        float4 xv = catv[(size_t)node * 16 + q * 4 + c];
        xv.x *= xv.x; xv.y *= xv.y; xv.z *= xv.z; xv.w *= xv.w;
#pragma unroll
        for (int r = 0; r < N_REL; ++r) {
            float4 wv = w2[r * 16 + q * 4 + c];
            acc[r] += xv.x * wv.x + xv.y * wv.y + xv.z * wv.z + xv.w * wv.w;
        }
    }
    // reduce across the 4 threads of this node (quad butterfly)
#pragma unroll
    for (int r = 0; r < N_REL; ++r) {
        acc[r] += __shfl_xor(acc[r], 1);
        acc[r] += __shfl_xor(acc[r], 2);
    }
    // each quarter-thread writes 8 rels (constant register indices per branch)
    float4* nv = (float4*)norm2;
    size_t base = (size_t)node * 8 + q * 2;
    if (q == 0) {
        nv[base]     = make_float4(acc[0],  acc[1],  acc[2],  acc[3]);
        nv[base + 1] = make_float4(acc[4],  acc[5],  acc[6],  acc[7]);
    } else if (q == 1) {
        nv[base]     = make_float4(acc[8],  acc[9],  acc[10], acc[11]);
        nv[base + 1] = make_float4(acc[12], acc[13], acc[14], acc[15]);
    } else if (q == 2) {
        nv[base]     = make_float4(acc[16], acc[17], acc[18], acc[19]);
        nv[base + 1] = make_float4(acc[20], acc[21], acc[22], acc[23]);
    } else {
        nv[base]     = make_float4(acc[24], acc[25], acc[26], acc[27]);
        nv[base + 1] = make_float4(acc[28], acc[29], acc[30], acc[31]);
    }
}

// per-WG LDS histogram over 392 coarse buckets, single flush
__global__ void coarse_hist_kernel(const int* __restrict__ head,
                                   const int* __restrict__ imr,
                                   int* __restrict__ ccnt) {
    __shared__ int h[NBK];
    int t = threadIdx.x;
    for (int i = t; i < NBK; i += 256) h[i] = 0;
    __syncthreads();
    int stride = gridDim.x * 256;
    for (int i = blockIdx.x * 256 + t; i < NEDGE + NNZ; i += stride) {
        if (i < NEDGE) atomicAdd(&h[head[i] >> EB_SHIFT], 1);
        else           atomicAdd(&h[NBKE + (imr[i - NEDGE] >> UB_SHIFT)], 1);
    }
    __syncthreads();
    for (int i = t; i < NBK; i += 256) if (h[i]) atomicAdd(&ccnt[i], h[i]);
}

// single-WG scan of 392 coarse bins -> bucket bases + cursors + sentinels
__global__ void coarse_scan_kernel(const int* __restrict__ ccnt,
                                   int* __restrict__ cbase_e, int* __restrict__ cbase_u,
                                   int* __restrict__ ccur_e,  int* __restrict__ ccur_u,
                                   int* __restrict__ offs_e,  int* __restrict__ offs_u) {
    __shared__ int sc[256];
    int t = threadIdx.x;
    int c = (t < NBKE) ? ccnt[t] : 0;
    sc[t] = c; __syncthreads();
    for (int off = 1; off < 256; off <<= 1) {
        int v = (t >= off) ? sc[t - off] : 0; __syncthreads();
        sc[t] += v; __syncthreads();
    }
    int excl = sc[t] - c;
    if (t < NBKE) { cbase_e[t] = excl; ccur_e[t] = excl; }
    if (t == NBKE - 1) cbase_e[NBKE] = excl + c;
    __syncthreads();
    c = (t < NBKU) ? ccnt[NBKE + t] : 0;
    sc[t] = c; __syncthreads();
    for (int off = 1; off < 256; off <<= 1) {
        int v = (t >= off) ? sc[t - off] : 0; __syncthreads();
        sc[t] += v; __syncthreads();
    }
    excl = sc[t] - c;
    if (t < NBKU) { cbase_u[t] = excl; ccur_u[t] = excl; }
    if (t == NBKU - 1) cbase_u[NBKU] = excl + c;
    if (t == 0) { offs_e[N_CAT] = NEDGE; offs_u[N_USERS] = NNZ; }
}

// pass1 edges: tile -> LDS count/scan -> ONE global atomic per (tile,bucket)
__global__ __launch_bounds__(256) void pass1_edges_kernel(
        const int* __restrict__ head, const int* __restrict__ tail,
        const int* __restrict__ etype, int* __restrict__ ccur_e,
        int* __restrict__ sorted_ta) {
    __shared__ int cnt[256], loc[256], base[256], sc[256];
    __shared__ int stage[T1];
    __shared__ int gpos[T1];
    int t = threadIdx.x;
    int tile = blockIdx.x * T1;
    cnt[t] = 0;
    __syncthreads();
    int rec[16], bk[16];
#pragma unroll
    for (int k = 0; k < 16; ++k) {
        int i = tile + k * 256 + t;
        if (i < NEDGE) {
            int h = head[i], tl = tail[i], r = etype[i] - 1;
            bk[k]  = h >> EB_SHIFT;
            rec[k] = ((h & (EB_SIZE - 1)) << 22) | (tl << 5) | r;
            atomicAdd(&cnt[bk[k]], 1);
        } else bk[k] = -1;
    }
    __syncthreads();
    int c = cnt[t];
    sc[t] = c; __syncthreads();
    for (int off = 1; off < 256; off <<= 1) {
        int v = (t >= off) ? sc[t - off] : 0; __syncthreads();
        sc[t] += v; __syncthreads();
    }
    loc[t] = sc[t] - c;
    if (t < NBKE && c > 0) base[t] = atomicAdd(&ccur_e[t], c);
    __syncthreads();
    cnt[t] = loc[t];
    __syncthreads();
#pragma unroll
    for (int k = 0; k < 16; ++k) {
        if (bk[k] >= 0) {
            int p = atomicAdd(&cnt[bk[k]], 1);
            stage[p] = rec[k];
            gpos[p]  = base[bk[k]] + (p - loc[bk[k]]);
        }
    }
    __syncthreads();
    int nv = min(T1, NEDGE - tile);
    for (int i = t; i < nv; i += 256) sorted_ta[gpos[i]] = stage[i];
}

__global__ __launch_bounds__(256) void pass1_users_kernel(
        const int* __restrict__ imr, const int* __restrict__ imc,
        const float* __restrict__ imv, int* __restrict__ ccur_u,
        int2* __restrict__ sorted_cv) {
    __shared__ int cnt[256], loc[256], base[256], sc[256];
    __shared__ int2 stage[T1];
    __shared__ int gpos[T1];
    int t = threadIdx.x;
    int tile = blockIdx.x * T1;
    cnt[t] = 0;
    __syncthreads();
    int2 rec[16]; int bk[16];
#pragma unroll
    for (int k = 0; k < 16; ++k) {
        int i = tile + k * 256 + t;
        if (i < NNZ) {
            int rr = imr[i];
            bk[k]  = rr >> UB_SHIFT;
            rec[k] = make_int2(((rr & (UB_SIZE - 1)) << 17) | imc[i],
                               __float_as_int(imv[i]));
            atomicAdd(&cnt[bk[k]], 1);
        } else bk[k] = -1;
    }
    __syncthreads();
    int c = cnt[t];
    sc[t] = c; __syncthreads();
    for (int off = 1; off < 256; off <<= 1) {
        int v = (t >= off) ? sc[t - off] : 0; __syncthreads();
        sc[t] += v; __syncthreads();
    }
    loc[t] = sc[t] - c;
    if (t < NBKU && c > 0) base[t] = atomicAdd(&ccur_u[t], c);
    __syncthreads();
    cnt[t] = loc[t];
    __syncthreads();
#pragma unroll
    for (int k = 0; k < 16; ++k) {
        if (bk[k] >= 0) {
            int p = atomicAdd(&cnt[bk[k]], 1);
            stage[p] = rec[k];
            gpos[p]  = base[bk[k]] + (p - loc[bk[k]]);
        }
    }
    __syncthreads();
    int nv = min(T1, NNZ - tile);
    for (int i = t; i < nv; i += 256) sorted_cv[gpos[i]] = stage[i];
}

// pass2: one WG per coarse bucket; fine counting-sort in LDS; writes fine offs
__global__ __launch_bounds__(256) void pass2_kernel(
        const int* __restrict__ cbase_e, const int* __restrict__ cbase_u,
        int* __restrict__ offs_e, int* __restrict__ offs_u,
        int* __restrict__ sorted_ta, int2* __restrict__ sorted_cv) {
    __shared__ int lds[UCAP * 2];        // 60 KB
    __shared__ int fh[EB_SIZE + 1];
    __shared__ int sc[256];
    int t = threadIdx.x;
    int b = blockIdx.x;
    if (b < NBKE) {
        int h0 = b << EB_SHIFT;
        int start = cbase_e[b], end = cbase_e[b + 1];
        int n = min(end - start, ECAP);
        for (int i = t; i < n; i += 256) lds[i] = sorted_ta[start + i];
        fh[2 * t] = 0; fh[2 * t + 1] = 0;
        __syncthreads();
        for (int i = t; i < n; i += 256) atomicAdd(&fh[lds[i] >> 22], 1);
        __syncthreads();
        int a = fh[2 * t], b2 = fh[2 * t + 1];
        sc[t] = a + b2; __syncthreads();
        for (int off = 1; off < 256; off <<= 1) {
            int v = (t >= off) ? sc[t - off] : 0; __syncthreads();
            sc[t] += v; __syncthreads();
        }
        int pe = sc[t] - (a + b2);
        int lim = min(EB_SIZE, N_CAT - h0);
        if (2 * t     < lim) offs_e[h0 + 2 * t]     = start + pe;
        if (2 * t + 1 < lim) offs_e[h0 + 2 * t + 1] = start + pe + a;
        fh[2 * t] = pe; fh[2 * t + 1] = pe + a;
        __syncthreads();
        for (int i = t; i < n; i += 256) {
            int rec = lds[i];
            int p = atomicAdd(&fh[rec >> 22], 1);
            sorted_ta[start + p] = rec & 0x3FFFFF;     // (tail<<5)|rel
        }
    } else {
        int k = b - NBKE;
        int u0 = k << UB_SHIFT;
        int start = cbase_u[k], end = cbase_u[k + 1];
        int n = min(end - start, UCAP);
        int2* lds2 = (int2*)lds;
        for (int i = t; i < n; i += 256) lds2[i] = sorted_cv[start + i];
        fh[t] = 0;
        __syncthreads();
        for (int i = t; i < n; i += 256) atomicAdd(&fh[lds2[i].x >> 17], 1);
        __syncthreads();
        int c = fh[t];
        sc[t] = c; __syncthreads();
        for (int off = 1; off < 256; off <<= 1) {
            int v = (t >= off) ? sc[t - off] : 0; __syncthreads();
            sc[t] += v; __syncthreads();
        }
        int excl = sc[t] - c;
        int lim = min(UB_SIZE, N_USERS - u0);
        if (t < lim) offs_u[u0 + t] = start + excl;
        fh[t] = excl;
        __syncthreads();
        for (int i = t; i < n; i += 256) {
            int2 rec = lds2[i];
            int p = atomicAdd(&fh[rec.x >> 17], 1);
            sorted_cv[start + p] = make_int2(rec.x & 0x1FFFF, rec.y);
        }
    }
}

// one wave per head; fast path deg<=64: single record read, softmax in registers
__global__ void cat_agg_sorted_kernel(const int* __restrict__ offs_e,
                                      const int* __restrict__ sorted_ta,
                                      const float* __restrict__ norm2,
                                      const float* __restrict__ cat,
                                      const float* __restrict__ W,
                                      float* __restrict__ cat_agg) {
    int wv   = threadIdx.x >> 6;
    int lane = threadIdx.x & 63;
    int h = blockIdx.x * 4 + wv;
    int start = offs_e[h];
    int end   = offs_e[h + 1];
    int deg   = end - start;

    float a0 = 0.f, a1 = 0.f, a2 = 0.f, a3 = 0.f;

    if (deg <= 64) {
        int   rec = 0;
        float att = -FLT_MAX;
        if (lane < deg) {
            rec = sorted_ta[start + lane];
            int tt = rec >> 5, r = rec & 31;
            att = norm2[h * N_REL + r] * norm2[(size_t)tt * N_REL + r];
        }
        float m = att;
#pragma unroll
        for (int off = 32; off > 0; off >>= 1) m = fmaxf(m, __shfl_xor(m, off));
        float ex = (lane < deg) ? __expf(att - m) : 0.f;
        float ssum = ex;
#pragma unroll
        for (int off = 32; off > 0; off >>= 1) ssum += __shfl_xor(ssum, off);
        float w = (deg > 0) ? ex / ssum : 0.f;

        int j = 0;
        for (; j + 4 <= deg; j += 4) {
            int   tr0 = __shfl(rec, j + 0), tr1 = __shfl(rec, j + 1);
            int   tr2 = __shfl(rec, j + 2), tr3 = __shfl(rec, j + 3);
            float w0  = __shfl(w,   j + 0), w1  = __shfl(w,   j + 1);
            float w2  = __shfl(w,   j + 2), w3  = __shfl(w,   j + 3);
            a0 += w0 * cat[(size_t)(tr0 >> 5) * D + lane] * W[(tr0 & 31) * D + lane];
            a1 += w1 * cat[(size_t)(tr1 >> 5) * D + lane] * W[(tr1 & 31) * D + lane];
            a2 += w2 * cat[(size_t)(tr2 >> 5) * D + lane] * W[(tr2 & 31) * D + lane];
            a3 += w3 * cat[(size_t)(tr3 >> 5) * D + lane] * W[(tr3 & 31) * D + lane];
        }
        for (; j < deg; ++j) {
            int   tr = __shfl(rec, j);
            float ww = __shfl(w,   j);
            a0 += ww * cat[(size_t)(tr >> 5) * D + lane] * W[(tr & 31) * D + lane];
        }
    } else {
        float m = -FLT_MAX;
        for (int j = lane; j < deg; j += 64) {
            int rec = sorted_ta[start + j];
            int tt = rec >> 5, r = rec & 31;
            m = fmaxf(m, norm2[h * N_REL + r] * norm2[(size_t)tt * N_REL + r]);
        }
#pragma unroll
        for (int off = 32; off > 0; off >>= 1) m = fmaxf(m, __shfl_xor(m, off));
        float ssum = 0.f;
        for (int j = lane; j < deg; j += 64) {
            int rec = sorted_ta[start + j];
            int tt = rec >> 5, r = rec & 31;
            ssum += __expf(norm2[h * N_REL + r] * norm2[(size_t)tt * N_REL + r] - m);
        }
#pragma unroll
        for (int off = 32; off > 0; off >>= 1) ssum += __shfl_xor(ssum, off);
        float inv = 1.f / ssum;
        for (int j0 = 0; j0 < deg; j0 += 64) {
            int n = min(64, deg - j0);
            int   rec = 0;
            float w   = 0.f;
            if (lane < n) {
                rec = sorted_ta[start + j0 + lane];
                int tt = rec >> 5, r = rec & 31;
                w = __expf(norm2[h * N_REL + r] * norm2[(size_t)tt * N_REL + r] - m) * inv;
            }
            for (int j = 0; j < n; ++j) {
                int   tr = __shfl(rec, j);
                float ww = __shfl(w,   j);
                a0 += ww * cat[(size_t)(tr >> 5) * D + lane] * W[(tr & 31) * D + lane];
            }
        }
    }
    cat_agg[(size_t)h * D + lane] = (a0 + a1) + (a2 + a3);
}

__global__ void spmm_user_kernel(const int* __restrict__ offs_u,
                                 const int2* __restrict__ sorted_cv,
                                 const float* __restrict__ cat,
                                 const float* __restrict__ uemb,
                                 const float* __restrict__ W,
                                 float* __restrict__ uagg) {
    __shared__ float s_user[4][D];
    __shared__ float s_score[4][N_REL];
    int wv   = threadIdx.x >> 6;
    int lane = threadIdx.x & 63;
    int u = blockIdx.x * 4 + wv;
    int start = offs_u[u];
    int end   = offs_u[u + 1];
    int deg   = end - start;

    float a0 = 0.f, a1 = 0.f, a2 = 0.f, a3 = 0.f;
    for (int j0 = 0; j0 < deg; j0 += 64) {
        int n = min(64, deg - j0);
        int   my_c = 0;
        float my_v = 0.f;
        if (lane < n) {
            int2 cv = sorted_cv[start + j0 + lane];
            my_c = cv.x;
            my_v = __int_as_float(cv.y);
        }
        int j = 0;
        for (; j + 4 <= n; j += 4) {
            int   c0 = __shfl(my_c, j + 0), c1 = __shfl(my_c, j + 1);
            int   c2 = __shfl(my_c, j + 2), c3 = __shfl(my_c, j + 3);
            float v0 = __shfl(my_v, j + 0), v1 = __shfl(my_v, j + 1);
            float v2 = __shfl(my_v, j + 2), v3 = __shfl(my_v, j + 3);
            a0 += v0 * cat[(size_t)c0 * D + lane];
            a1 += v1 * cat[(size_t)c1 * D + lane];
            a2 += v2 * cat[(size_t)c2 * D + lane];
            a3 += v3 * cat[(size_t)c3 * D + lane];
        }
        for (; j < n; ++j) {
            int   cc = __shfl(my_c, j);
            float vv = __shfl(my_v, j);
            a0 += vv * cat[(size_t)cc * D + lane];
        }
    }
    float acc = (a0 + a1) + (a2 + a3);

    s_user[wv][lane] = uemb[(size_t)u * D + lane];
    __syncthreads();

    if (lane < N_REL) {
        float dot = 0.f;
#pragma unroll
        for (int d = 0; d < D; ++d) dot += s_user[wv][d] * W[lane * D + d];
        float mm = dot;
#pragma unroll
        for (int off = 16; off > 0; off >>= 1) mm = fmaxf(mm, __shfl_xor(mm, off));
        float ex = __expf(dot - mm);
        float sm = ex;
#pragma unroll
        for (int off = 16; off > 0; off >>= 1) sm += __shfl_xor(sm, off);
        s_score[wv][lane] = ex / sm;
    }
    __syncthreads();

    float proj = 0.f;
#pragma unroll
    for (int r = 0; r < N_REL; ++r) proj += s_score[wv][r] * W[r * D + lane];

    uagg[(size_t)u * D + lane] = acc * (1.f + proj);
}

extern "C" void kernel_launch(void* const* d_in, const int* in_sizes, int n_in,
                              void* d_out, int out_size, void* d_ws, size_t ws_size,
                              hipStream_t stream) {
    const float* cat   = (const float*)d_in[0];
    const float* uemb  = (const float*)d_in[1];
    const int*   eidx  = (const int*)d_in[2];
    const int*   etype = (const int*)d_in[3];
    const int*   imr   = (const int*)d_in[4];
    const int*   imc   = (const int*)d_in[5];
    const float* imv   = (const float*)d_in[6];
    const float* W     = (const float*)d_in[7];
    const int* head = eidx;
    const int* tail = eidx + NEDGE;

    float* out     = (float*)d_out;
    float* cat_agg = out;                         // [N_CAT, D]
    float* uagg    = out + (size_t)N_CAT * D;     // [N_USERS, D]

    float* norm2   = (float*)d_ws;
    int*   ccnt    = (int*)(norm2 + (size_t)N_CAT * N_REL);
    int*   cbase_e = ccnt + NBK;
    int*   cbase_u = cbase_e + NBKE + 1;
    int*   ccur_e  = cbase_u + NBKU + 1;
    int*   ccur_u  = ccur_e + NBKE;
    int*   offs_e  = ccur_u + NBKU;
    int*   offs_u  = offs_e + N_CAT + 1;
    int*   sorted_ta = offs_u + N_USERS + 1;
    int2*  sorted_cv = (int2*)(sorted_ta + NEDGE);

    hipMemsetAsync(ccnt, 0, (size_t)NBK * sizeof(int), stream);

    coarse_hist_kernel<<<512, 256, 0, stream>>>(head, imr, ccnt);
    coarse_scan_kernel<<<1, 256, 0, stream>>>(ccnt, cbase_e, cbase_u,
                                              ccur_e, ccur_u, offs_e, offs_u);
    pass1_edges_kernel<<<(NEDGE + T1 - 1) / T1, 256, 0, stream>>>(
        head, tail, etype, ccur_e, sorted_ta);
    pass1_users_kernel<<<(NNZ + T1 - 1) / T1, 256, 0, stream>>>(
        imr, imc, imv, ccur_u, sorted_cv);
    pass2_kernel<<<NBK, 256, 0, stream>>>(cbase_e, cbase_u, offs_e, offs_u,
                                          sorted_ta, sorted_cv);
    norm2_kernel<<<(N_CAT + 63) / 64, 256, 0, stream>>>(cat, W, norm2);
    cat_agg_sorted_kernel<<<N_CAT / 4, 256, 0, stream>>>(offs_e, sorted_ta, norm2, cat, W, cat_agg);
    spmm_user_kernel<<<N_USERS / 4, 256, 0, stream>>>(offs_u, sorted_cv, cat, uemb, W, uagg);
}